// Round 2
// baseline (271.492 us; speedup 1.0000x reference)
//
#include <hip/hip_runtime.h>
#include <hip/hip_bf16.h>
#include <cstddef>

// Problem constants (from reference setup_inputs):
//   x: (B=8, C=64, H=256, W=256) fp32
//   w_sub: (C,LD=8), b_sub: (LD), w_up: (LD,C), b_up: (C), mb: (LD,MEM=128), mu: (1)
constexpr int B = 8, C = 64, H = 256, W = 256, LD = 8, MEM = 128;
constexpr int W4 = W / 4;       // 64 float4 per row
constexpr int NSTRIPE = B * W;  // 2048
constexpr int NQ = 4;           // quarters of H per partial-sum block
constexpr int ROWS = 32;        // rows of a plane per k_scale block

// ---------------------------------------------------------------------------
// Kernel 1: partial H-sums. One block per (b,c,quarter): sums 64 rows.
// part[((b*C+c)*NQ + q)*W + w] = sum_{h in quarter q} x[b,c,h,w]
// 2048 blocks x 4 waves = 32 waves/CU -> enough loads in flight for HBM BW.
// ---------------------------------------------------------------------------
__global__ __launch_bounds__(256) void k_mean_part(const float* __restrict__ x,
                                                   float4* __restrict__ part4) {
    const int gb = blockIdx.x;          // (b*C+c)*NQ + q
    const int bc = gb >> 2;
    const int q  = gb & 3;
    const int t  = threadIdx.x;
    const int w4 = t & 63;
    const int hg = t >> 6;              // 0..3

    const float4* plane = reinterpret_cast<const float4*>(x + (size_t)bc * H * W);
    float sx = 0.f, sy = 0.f, sz = 0.f, sw = 0.f;
    const int h0 = q * 64 + hg;
    #pragma unroll
    for (int i = 0; i < 16; ++i) {
        float4 v = plane[(h0 + i * 4) * W4 + w4];
        sx += v.x; sy += v.y; sz += v.z; sw += v.w;
    }

    __shared__ float4 red[256];
    red[t] = make_float4(sx, sy, sz, sw);
    __syncthreads();

    if (hg == 0) {
        float4 a = red[t], p1 = red[t + 64], p2 = red[t + 128], p3 = red[t + 192];
        float4 r;
        r.x = a.x + p1.x + p2.x + p3.x;
        r.y = a.y + p1.y + p2.y + p3.y;
        r.z = a.z + p1.z + p2.z + p3.z;
        r.w = a.w + p1.w + p2.w + p3.w;
        part4[(size_t)gb * W4 + w4] = r;   // flat float idx: gb*W + w
    }
}

// ---------------------------------------------------------------------------
// Kernel 2: per-stripe gate, wave-parallel. One block (128 thr) per stripe s.
//   y    = mean over H (finalize the 4 partials)         (C=64)
//   low  = y @ w_sub + b_sub                             (LD=8)
//   f    = softmax(low @ mb * LD^-0.5)                   (MEM=128)
//   y1   = f @ mb^T                                      (LD=8)
//   gate = sigmoid(y1 @ w_up + b_up) * mu                (C=64)
// Stored transposed: gateT[c*NSTRIPE + s] so k_scale reads coalesced.
// 16-lane-group dot products + __shfl_xor reduces; 6 barriers total.
// ---------------------------------------------------------------------------
__global__ __launch_bounds__(128) void k_gate(const float* __restrict__ part,
                                              const float* __restrict__ w_sub,
                                              const float* __restrict__ b_sub,
                                              const float* __restrict__ w_up,
                                              const float* __restrict__ b_up,
                                              const float* __restrict__ mb,
                                              const float* __restrict__ mu,
                                              float* __restrict__ gateT) {
    const int s = blockIdx.x;
    const int b = s >> 8;               // W = 256
    const int w = s & 255;
    const int t = threadIdx.x;

    __shared__ float y[C];
    __shared__ float low[LD];
    __shared__ float f[MEM];            // unnormalized exp
    __shared__ float wred[4];           // [0:2) wave max, [2:4) wave sum
    __shared__ float y1[LD];
    __shared__ float red2[128];

    // --- Phase A: finalize mean. thread t -> channel c=t&63, quarter-half qh=t>>6
    {
        const int c  = t & 63;
        const int qh = t >> 6;          // 0..1 -> quarters {0,1} or {2,3}
        const float* pc = part + (((size_t)(b * C + c) * NQ + qh * 2) * W + w);
        red2[t] = pc[0] + pc[W];
        __syncthreads();
        if (t < C) y[t] = (red2[t] + red2[t + 64]) * (1.0f / (float)H);
        __syncthreads();
    }

    const int l = t >> 4;               // 0..7
    const int i = t & 15;               // 0..15 (within-wave 16-group)

    // --- Phase B: low[l] = b_sub[l] + sum_c y[c] * w_sub[c*LD+l]
    {
        float acc = 0.f;
        #pragma unroll
        for (int j = 0; j < 4; ++j) {
            const int c = i + 16 * j;
            acc += y[c] * w_sub[c * LD + l];
        }
        acc += __shfl_xor(acc, 1);
        acc += __shfl_xor(acc, 2);
        acc += __shfl_xor(acc, 4);
        acc += __shfl_xor(acc, 8);
        if (i == 0) low[l] = acc + b_sub[l];
    }
    __syncthreads();

    // --- Phase C: f1[t] + softmax over 128 (2 waves)
    float v = 0.f;
    #pragma unroll
    for (int ll = 0; ll < LD; ++ll) v += low[ll] * mb[ll * MEM + t];
    v *= 0.35355339059327373f;          // 8^-0.5

    float m = v;
    #pragma unroll
    for (int mask = 1; mask <= 32; mask <<= 1) m = fmaxf(m, __shfl_xor(m, mask));
    const int wid = t >> 6;
    if ((t & 63) == 0) wred[wid] = m;
    __syncthreads();
    m = fmaxf(wred[0], wred[1]);

    const float e = expf(v - m);
    f[t] = e;                           // unnormalized; normalize in phase D
    float sm = e;
    #pragma unroll
    for (int mask = 1; mask <= 32; mask <<= 1) sm += __shfl_xor(sm, mask);
    if ((t & 63) == 0) wred[2 + wid] = sm;
    __syncthreads();
    const float invsum = 1.0f / (wred[2] + wred[3]);

    // --- Phase D: y1[l] = invsum * sum_k e[k] * mb[l*MEM+k]
    {
        float acc = 0.f;
        #pragma unroll
        for (int j = 0; j < 8; ++j) {
            const int k = i * 8 + j;
            acc += f[k] * mb[l * MEM + k];
        }
        acc += __shfl_xor(acc, 1);
        acc += __shfl_xor(acc, 2);
        acc += __shfl_xor(acc, 4);
        acc += __shfl_xor(acc, 8);
        if (i == 0) y1[l] = acc * invsum;
    }
    __syncthreads();

    // --- Phase E: gate = sigmoid(y1 @ w_up + b_up) * mu, stored transposed
    if (t < C) {
        float acc = b_up[t];
        #pragma unroll
        for (int ll = 0; ll < LD; ++ll) acc += y1[ll] * w_up[ll * C + t];
        const float g = mu[0] / (1.0f + expf(-acc));
        gateT[(size_t)t * NSTRIPE + s] = g;
    }
}

// ---------------------------------------------------------------------------
// Kernel 3: out[b,c,h,w] = x[b,c,h,w] * gateT[c*NSTRIPE + b*W + w]
// grid = (H/ROWS, B*C), block = 256. Pure float4 stream; gate load is one
// coalesced 1 KiB read into LDS, then 4 register gates per thread.
// ---------------------------------------------------------------------------
__global__ __launch_bounds__(256) void k_scale(const float* __restrict__ x,
                                               const float* __restrict__ gateT,
                                               float* __restrict__ out) {
    const int bc = blockIdx.y;
    const int b  = bc >> 6;
    const int c  = bc & 63;
    const int t  = threadIdx.x;

    __shared__ float g[W];
    g[t] = gateT[(size_t)c * NSTRIPE + b * W + t];   // blockDim == W == 256
    __syncthreads();

    const int w4 = t & 63;              // invariant float4 column for this thread
    const float4 gv = reinterpret_cast<const float4*>(g)[w4];

    const float4* xp = reinterpret_cast<const float4*>(x + (size_t)bc * H * W);
    float4* op       = reinterpret_cast<float4*>(out + (size_t)bc * H * W);

    const int base = blockIdx.x * (ROWS * W4);
    #pragma unroll 8
    for (int idx = base + t; idx < base + ROWS * W4; idx += 256) {
        float4 v = xp[idx];
        v.x *= gv.x; v.y *= gv.y; v.z *= gv.z; v.w *= gv.w;
        op[idx] = v;
    }
}

extern "C" void kernel_launch(void* const* d_in, const int* in_sizes, int n_in,
                              void* d_out, int out_size, void* d_ws, size_t ws_size,
                              hipStream_t stream) {
    const float* x     = (const float*)d_in[0];
    const float* w_sub = (const float*)d_in[1];
    const float* b_sub = (const float*)d_in[2];
    const float* w_up  = (const float*)d_in[3];
    const float* b_up  = (const float*)d_in[4];
    const float* mb    = (const float*)d_in[5];
    const float* mu    = (const float*)d_in[6];
    float* out = (float*)d_out;

    // Workspace: part (B*C*NQ*W f32 = 2 MiB) + gateT (C*NSTRIPE f32 = 512 KiB)
    float* part  = (float*)d_ws;
    float* gateT = part + (size_t)B * C * NQ * W;

    k_mean_part<<<B * C * NQ, 256, 0, stream>>>(x, (float4*)part);
    k_gate<<<NSTRIPE, 128, 0, stream>>>(part, w_sub, b_sub, w_up, b_up, mb, mu, gateT);
    k_scale<<<dim3(H / ROWS, B * C), 256, 0, stream>>>(x, gateT, out);
}